// Round 8
// baseline (406.987 us; speedup 1.0000x reference)
//
#include <hip/hip_runtime.h>

typedef float f2 __attribute__((ext_vector_type(2)));

constexpr int Tt = 512;    // sequence length
constexpr int Bb = 256;    // batch
constexpr int Ee = 200;    // word-embedding dim
constexpr int Gg = 96;     // 4*H
constexpr int Vv = 50000;  // vocab

__device__ __forceinline__ float fast_rcp(float x) { return __builtin_amdgcn_rcpf(x); }
__device__ __forceinline__ float sigf(float x) { return fast_rcp(1.f + __expf(-x)); }
__device__ __forceinline__ float tanhf_(float x) {
    float e = __expf(2.f * x);
    return 1.f - 2.f * fast_rcp(e + 1.f);
}

// ---------------------------------------------------------------------------
// Kernel A: EwW[w][j*4+c] = sum_k Ew[w][k] * Wl[k][c*24+j]   (gate-interleaved)
// GEMM 50000 x 200 x 96 fp32. BM=64 BN=96 BK=8, thread tile 4x6 (f2-packed).
// ---------------------------------------------------------------------------
__global__ __launch_bounds__(256) void ew_proj(const float* __restrict__ Ew,
                                               const float* __restrict__ Wl,
                                               float* __restrict__ EwW)
{
    __shared__ float As[8][64];   // [k][m]
    __shared__ float Bs[8][96];   // [k][gate-interleaved col]
    const int tid = threadIdx.x;
    const int w0  = blockIdx.x * 64;
    const int tr  = tid >> 4;        // 0..15 -> rows tr*4..+3
    const int tc  = tid & 15;        // 0..15 -> cols tc*6..+5
    const int am  = tid >> 2;        // 0..63  (A stage row)
    const int ak  = (tid & 3) * 2;   // 0,2,4,6 (A stage k pair)
    const int bk  = tid >> 5;        // 0..7   (B stage k)
    const int bg  = (tid & 31) * 3;  // 0..93  (B stage col group)

    f2 acc[4][3] = {};

    for (int k0 = 0; k0 < Ee; k0 += 8) {
        // stage A tile (64 rows x 8 k), transposed to [k][m]
        {
            const int w = w0 + am;
            f2 av = {0.f, 0.f};
            if (w < Vv) av = *(const f2*)(Ew + (long)w * Ee + k0 + ak);
            As[ak][am]     = av.x;
            As[ak + 1][am] = av.y;
        }
        // stage B tile (8 k x 96), permuted to gate-interleaved column order
        #pragma unroll
        for (int u = 0; u < 3; ++u) {
            const int g  = bg + u;
            const int gp = (g % 24) * 4 + (g / 24);
            Bs[bk][gp] = Wl[(k0 + bk) * Gg + g];
        }
        __syncthreads();
        #pragma unroll
        for (int kk = 0; kk < 8; ++kk) {
            const float4 a4 = *(const float4*)&As[kk][tr * 4];
            f2 b[3];
            #pragma unroll
            for (int u = 0; u < 3; ++u) b[u] = *(const f2*)&Bs[kk][tc * 6 + u * 2];
            #pragma unroll
            for (int i = 0; i < 4; ++i) {
                const float ai = (&a4.x)[i];
                f2 a2 = {ai, ai};
                #pragma unroll
                for (int u = 0; u < 3; ++u) acc[i][u] += a2 * b[u];
            }
        }
        __syncthreads();
    }
    #pragma unroll
    for (int i = 0; i < 4; ++i) {
        const int w = w0 + tr * 4 + i;
        if (w < Vv) {
            #pragma unroll
            for (int u = 0; u < 3; ++u)
                *(f2*)(EwW + (long)w * Gg + tc * 6 + u * 2) = acc[i][u];
        }
    }
}

// ---------------------------------------------------------------------------
// Kernel C: sequential LSTM + mean-pool + MLP head.
// 1 wave per block, 2 batch chains per wave (lanes 0-23 / 32-55 own unit j).
// NO LDS / NO barrier in the loop: h broadcast via ds_swizzle (group-of-32
// lane-k broadcast), so prefetched gathers are never force-drained by a
// barrier's vmcnt(0).
// ---------------------------------------------------------------------------
#define REP24(M) M(0)M(1)M(2)M(3)M(4)M(5)M(6)M(7)M(8)M(9)M(10)M(11) \
                 M(12)M(13)M(14)M(15)M(16)M(17)M(18)M(19)M(20)M(21)M(22)M(23)

__global__ __launch_bounds__(64, 1) void lstm_head(
    const int* __restrict__ words, const int* __restrict__ caps,
    const float* __restrict__ Ec,  const float* __restrict__ Wl,
    const float* __restrict__ bl,  const float* __restrict__ EwW,
    const float* __restrict__ W1,  const float* __restrict__ b1,
    const float* __restrict__ W2,  const float* __restrict__ b2,
    float* __restrict__ out)
{
    __shared__ float4 EcB[3][24];     // cap -> per-unit (i,j,f,o) incl. b_lstm
    __shared__ float  hmean[2][24];
    __shared__ float  a1buf[2][50];

    const int  lane = threadIdx.x;
    const int  half = lane >> 5;
    const int  j    = lane & 31;
    const int  jc   = (j < 24) ? j : 23;  // clamp for safe (ignored) work
    const bool act  = (j < 24);
    const int  b    = blockIdx.x * 2 + half;

    // EcB[cap][unit] = Ec[cap] @ Wl[200:203] + b_lstm   (gate-interleaved)
    for (int e = lane; e < 72; e += 64) {
        const int cap = e / 24, jj = e % 24;
        float4 v;
        #pragma unroll
        for (int c = 0; c < 4; ++c) {
            float s = bl[c * 24 + jj];
            #pragma unroll
            for (int kk = 0; kk < 3; ++kk)
                s += Ec[cap * 3 + kk] * Wl[(200 + kk) * Gg + c * 24 + jj];
            (&v.x)[c] = s;
        }
        EcB[cap][jj] = v;
    }
    __syncthreads();

    // recurrent weights: lane j's 4 U-columns, forced into named registers
#define DECL_U(K) f2 uij##K, ufo##K;
    REP24(DECL_U)
#undef DECL_U
#define LOAD_U(K) { const int base_ = (203 + K) * Gg + jc;      \
                    uij##K.x = Wl[base_ +  0];                  \
                    uij##K.y = Wl[base_ + 24];                  \
                    ufo##K.x = Wl[base_ + 48];                  \
                    ufo##K.y = Wl[base_ + 72]; }
    REP24(LOAD_U)
#undef LOAD_U

    const int* wrow = words + b * Tt;
    const int* crow = caps  + b * Tt;
    const int  off  = jc * 4;

    // software pipeline: x ready/in-flight for t..t+2, x issued at t for t+3
    float4 x0 = *(const float4*)(EwW + (long)wrow[0] * Gg + off);
    float4 x1 = *(const float4*)(EwW + (long)wrow[1] * Gg + off);
    float4 x2 = *(const float4*)(EwW + (long)wrow[2] * Gg + off);
    int wi3 = wrow[3], wi4 = wrow[4];
    int cp0 = crow[0], cp1 = crow[1], cp2 = crow[2], cp3 = crow[3], cp4 = crow[4];

    float4 ecb = EcB[cp0][jc];    // prefetched add-in for current step
    float cstate = 0.f, hsum = 0.f, hn = 0.f;

    for (int t = 0; t < Tt; ++t) {
        // issue gather for t+3, index loads for t+5
        const float4 x3 = *(const float4*)(EwW + (long)wi3 * Gg + off);
        const int tn  = (t + 5 < Tt) ? (t + 5) : (Tt - 1);
        const int win = wrow[tn];
        const int cpn = crow[tn];

        f2 zij_a, zfo_a, zij_b = {0.f, 0.f}, zfo_b = {0.f, 0.f};
        zij_a.x = x0.x + ecb.x;  zij_a.y = x0.y + ecb.y;
        zfo_a.x = x0.z + ecb.z;  zfo_a.y = x0.w + ecb.w;

        const int hu = __float_as_int(hn);   // previous h, this lane's unit
#define STEP_A(K) { const float hk_ = __int_as_float(                          \
                        __builtin_amdgcn_ds_swizzle(hu, ((K) << 5)));          \
                    f2 h2_ = {hk_, hk_};                                       \
                    zij_a += h2_ * uij##K;  zfo_a += h2_ * ufo##K; }
#define STEP_B(K) { const float hk_ = __int_as_float(                          \
                        __builtin_amdgcn_ds_swizzle(hu, ((K) << 5)));          \
                    f2 h2_ = {hk_, hk_};                                       \
                    zij_b += h2_ * uij##K;  zfo_b += h2_ * ufo##K; }
        STEP_A(0)  STEP_A(1)  STEP_A(2)  STEP_A(3)  STEP_A(4)  STEP_A(5)
        STEP_A(6)  STEP_A(7)  STEP_A(8)  STEP_A(9)  STEP_A(10) STEP_A(11)
        STEP_B(12) STEP_B(13) STEP_B(14) STEP_B(15) STEP_B(16) STEP_B(17)
        STEP_B(18) STEP_B(19) STEP_B(20) STEP_B(21) STEP_B(22) STEP_B(23)
#undef STEP_A
#undef STEP_B

        const f2 zij = zij_a + zij_b;
        const f2 zfo = zfo_a + zfo_b;

        const float ig = sigf(zij.x);
        const float tj = tanhf_(zij.y);
        const float fg = sigf(zfo.x + 1.0f);   // forget bias
        const float og = sigf(zfo.y);
        cstate = fg * cstate + ig * tj;
        hn = og * tanhf_(cstate);
        hsum += hn;

        // prefetch next step's cap add-in, rotate pipeline
        ecb = EcB[cp1][jc];
        x0 = x1; x1 = x2; x2 = x3;
        wi3 = wi4; wi4 = win;
        cp0 = cp1; cp1 = cp2; cp2 = cp3; cp3 = cp4; cp4 = cpn;
    }

    // ---- epilogue: mean-pool + MLP head -----------------------------------
    if (act) hmean[half][jc] = hsum * (1.f / (float)Tt);
    __syncthreads();

    if (j < 25) {
        #pragma unroll
        for (int p = 0; p < 2; ++p) {
            const int q = j + p * 25;
            float s = b1[q];
            #pragma unroll
            for (int k = 0; k < 24; ++k)
                s += hmean[half][k] * W1[k * 50 + q];
            a1buf[half][q] = (s > 0.f) ? s : (__expf(s) - 1.f);  // ELU
        }
    }
    __syncthreads();

    if (j < 6) {
        float s = b2[j];
        for (int q = 0; q < 50; ++q) s += a1buf[half][q] * W2[q * 6 + j];
        out[b * 6 + j] = sigf(s);
    }
}

// ---------------------------------------------------------------------------
extern "C" void kernel_launch(void* const* d_in, const int* in_sizes, int n_in,
                              void* d_out, int out_size, void* d_ws, size_t ws_size,
                              hipStream_t stream)
{
    const int*   words = (const int*)d_in[0];
    const int*   caps  = (const int*)d_in[1];
    const float* Ew    = (const float*)d_in[2];
    const float* Ec    = (const float*)d_in[3];
    const float* Wl    = (const float*)d_in[4];
    const float* bl    = (const float*)d_in[5];
    const float* W1    = (const float*)d_in[6];
    const float* b1    = (const float*)d_in[7];
    const float* W2    = (const float*)d_in[8];
    const float* b2    = (const float*)d_in[9];
    float* out = (float*)d_out;
    float* EwW = (float*)d_ws;   // 50000 * 96 floats = 19.2 MB scratch

    ew_proj<<<(Vv + 63) / 64, 256, 0, stream>>>(Ew, Wl, EwW);
    lstm_head<<<Bb / 2, 64, 0, stream>>>(words, caps, Ec, Wl, bl, EwW,
                                         W1, b1, W2, b2, out);
}

// Round 10
// 406.606 us; speedup vs baseline: 1.0009x; 1.0009x over previous
//
#include <hip/hip_runtime.h>

typedef float f2 __attribute__((ext_vector_type(2)));

constexpr int Tt = 512;    // sequence length
constexpr int Bb = 256;    // batch
constexpr int Ee = 200;    // word-embedding dim
constexpr int Gg = 96;     // 4*H
constexpr int Vv = 50000;  // vocab

__device__ __forceinline__ float fast_rcp(float x) { return __builtin_amdgcn_rcpf(x); }
__device__ __forceinline__ float sigf(float x) { return fast_rcp(1.f + __expf(-x)); }
__device__ __forceinline__ float tanhf_(float x) {
    float e = __expf(2.f * x);
    return 1.f - 2.f * fast_rcp(e + 1.f);
}

// ---------------------------------------------------------------------------
// Kernel A: EwW[w][j*4+c] = sum_k Ew[w][k] * Wl[k][c*24+j]   (gate-interleaved)
// GEMM 50000 x 200 x 96 fp32. BM=64 BN=96 BK=8, thread tile 4x6 (f2-packed).
// Register-staged double buffer: tile k0+8's global loads are issued right
// after the first barrier so their latency drains under the 8-kk compute,
// instead of sitting on the critical path before every barrier.
// ---------------------------------------------------------------------------
__global__ __launch_bounds__(256) void ew_proj(const float* __restrict__ Ew,
                                               const float* __restrict__ Wl,
                                               float* __restrict__ EwW)
{
    __shared__ float As[8][64];   // [k][m]
    __shared__ float Bs[8][96];   // [k][gate-interleaved col]
    const int tid = threadIdx.x;
    const int w0  = blockIdx.x * 64;
    const int tr  = tid >> 4;        // 0..15 -> rows tr*4..+3
    const int tc  = tid & 15;        // 0..15 -> cols tc*6..+5
    const int am  = tid >> 2;        // 0..63  (A stage row)
    const int ak  = (tid & 3) * 2;   // 0,2,4,6 (A stage k pair)
    const int bk  = tid >> 5;        // 0..7   (B stage k)
    const int bg  = (tid & 31) * 3;  // 0..93  (B stage col group)

    const int wA = w0 + am;
    const float* aptr = Ew + (long)((wA < Vv) ? wA : (Vv - 1)) * Ee + ak;
    const float* bptr = Wl + bk * Gg + bg;
    int gp[3];
    #pragma unroll
    for (int u = 0; u < 3; ++u) { const int g = bg + u; gp[u] = (g % 24) * 4 + g / 24; }

    // prologue: stage k0=0 tile into registers
    f2    avr  = *(const f2*)(aptr);
    float bvr0 = bptr[0], bvr1 = bptr[1], bvr2 = bptr[2];

    f2 acc[4][3] = {};

    for (int k0 = 0; k0 < Ee; k0 += 8) {
        // write staged registers to LDS
        As[ak][am]     = avr.x;
        As[ak + 1][am] = avr.y;
        Bs[bk][gp[0]] = bvr0; Bs[bk][gp[1]] = bvr1; Bs[bk][gp[2]] = bvr2;
        __syncthreads();

        // issue next tile's loads — latency hidden under compute below
        if (k0 + 8 < Ee) {
            avr  = *(const f2*)(aptr + k0 + 8);
            const long bo = (long)(k0 + 8) * Gg;
            bvr0 = bptr[bo + 0]; bvr1 = bptr[bo + 1]; bvr2 = bptr[bo + 2];
        }

        #pragma unroll
        for (int kk = 0; kk < 8; ++kk) {
            const float4 a4 = *(const float4*)&As[kk][tr * 4];
            f2 b[3];
            #pragma unroll
            for (int u = 0; u < 3; ++u) b[u] = *(const f2*)&Bs[kk][tc * 6 + u * 2];
            #pragma unroll
            for (int i = 0; i < 4; ++i) {
                const float ai = (&a4.x)[i];
                f2 a2 = {ai, ai};
                #pragma unroll
                for (int u = 0; u < 3; ++u) acc[i][u] += a2 * b[u];
            }
        }
        __syncthreads();
    }
    #pragma unroll
    for (int i = 0; i < 4; ++i) {
        const int w = w0 + tr * 4 + i;
        if (w < Vv) {
            #pragma unroll
            for (int u = 0; u < 3; ++u)
                *(f2*)(EwW + (long)w * Gg + tc * 6 + u * 2) = acc[i][u];
        }
    }
}

// ---------------------------------------------------------------------------
// Kernel C: sequential LSTM + mean-pool + MLP head.
// 1 wave per block, 2 batch chains per wave (lanes 0-23 / 32-55 own unit j).
// No LDS/barrier in the loop (h broadcast via ds_swizzle). U weights are
// PINNED in VGPRs via asm volatile "+v": round-8 counters (VGPR=88) proved
// LLVM rematerialized the U loads into the loop; making each value an asm
// output forbids re-loading it from memory.
// ---------------------------------------------------------------------------
#define REP24(M) M(0)M(1)M(2)M(3)M(4)M(5)M(6)M(7)M(8)M(9)M(10)M(11) \
                 M(12)M(13)M(14)M(15)M(16)M(17)M(18)M(19)M(20)M(21)M(22)M(23)

__global__ __launch_bounds__(64, 1) void lstm_head(
    const int* __restrict__ words, const int* __restrict__ caps,
    const float* __restrict__ Ec,  const float* __restrict__ Wl,
    const float* __restrict__ bl,  const float* __restrict__ EwW,
    const float* __restrict__ W1,  const float* __restrict__ b1,
    const float* __restrict__ W2,  const float* __restrict__ b2,
    float* __restrict__ out)
{
    __shared__ float4 EcB[3][24];     // cap -> per-unit (i,j,f,o) incl. b_lstm
    __shared__ float  hmean[2][24];
    __shared__ float  a1buf[2][50];

    const int  lane = threadIdx.x;
    const int  half = lane >> 5;
    const int  j    = lane & 31;
    const int  jc   = (j < 24) ? j : 23;  // clamp for safe (ignored) work
    const bool act  = (j < 24);
    const int  b    = blockIdx.x * 2 + half;

    // EcB[cap][unit] = Ec[cap] @ Wl[200:203] + b_lstm   (gate-interleaved)
    for (int e = lane; e < 72; e += 64) {
        const int cap = e / 24, jj = e % 24;
        float4 v;
        #pragma unroll
        for (int c = 0; c < 4; ++c) {
            float s = bl[c * 24 + jj];
            #pragma unroll
            for (int kk = 0; kk < 3; ++kk)
                s += Ec[cap * 3 + kk] * Wl[(200 + kk) * Gg + c * 24 + jj];
            (&v.x)[c] = s;
        }
        EcB[cap][jj] = v;
    }
    __syncthreads();

    // recurrent weights: lane j's 4 U-columns, loaded then PINNED in VGPRs
#define DECL_U(K) f2 uij##K, ufo##K;
    REP24(DECL_U)
#undef DECL_U
#define LOAD_U(K) { const int base_ = (203 + K) * Gg + jc;      \
                    uij##K.x = Wl[base_ +  0];                  \
                    uij##K.y = Wl[base_ + 24];                  \
                    ufo##K.x = Wl[base_ + 48];                  \
                    ufo##K.y = Wl[base_ + 72]; }
    REP24(LOAD_U)
#undef LOAD_U
    // Forbid rematerialization: each value becomes an asm output the
    // compiler cannot re-derive from memory.
#define PIN_U(K) asm volatile("" : "+v"(uij##K), "+v"(ufo##K));
    REP24(PIN_U)
#undef PIN_U

    const int* wrow = words + b * Tt;
    const int* crow = caps  + b * Tt;
    const int  off  = jc * 4;

    // software pipeline: x ready/in-flight for t..t+2, x issued at t for t+3
    float4 x0 = *(const float4*)(EwW + (long)wrow[0] * Gg + off);
    float4 x1 = *(const float4*)(EwW + (long)wrow[1] * Gg + off);
    float4 x2 = *(const float4*)(EwW + (long)wrow[2] * Gg + off);
    int wi3 = wrow[3], wi4 = wrow[4];
    int cp0 = crow[0], cp1 = crow[1], cp2 = crow[2], cp3 = crow[3], cp4 = crow[4];

    float4 ecb = EcB[cp0][jc];    // prefetched add-in for current step
    float cstate = 0.f, hsum = 0.f, hn = 0.f;

    for (int t = 0; t < Tt; ++t) {
        // issue gather for t+3, index loads for t+5
        const float4 x3 = *(const float4*)(EwW + (long)wi3 * Gg + off);
        const int tn  = (t + 5 < Tt) ? (t + 5) : (Tt - 1);
        const int win = wrow[tn];
        const int cpn = crow[tn];

        f2 zij_a, zfo_a, zij_b = {0.f, 0.f}, zfo_b = {0.f, 0.f};
        zij_a.x = x0.x + ecb.x;  zij_a.y = x0.y + ecb.y;
        zfo_a.x = x0.z + ecb.z;  zfo_a.y = x0.w + ecb.w;

        const int hu = __float_as_int(hn);   // previous h, this lane's unit
#define STEP_A(K) { const float hk_ = __int_as_float(                          \
                        __builtin_amdgcn_ds_swizzle(hu, ((K) << 5)));          \
                    f2 h2_ = {hk_, hk_};                                       \
                    zij_a += h2_ * uij##K;  zfo_a += h2_ * ufo##K; }
#define STEP_B(K) { const float hk_ = __int_as_float(                          \
                        __builtin_amdgcn_ds_swizzle(hu, ((K) << 5)));          \
                    f2 h2_ = {hk_, hk_};                                       \
                    zij_b += h2_ * uij##K;  zfo_b += h2_ * ufo##K; }
        STEP_A(0)  STEP_A(1)  STEP_A(2)  STEP_A(3)  STEP_A(4)  STEP_A(5)
        STEP_A(6)  STEP_A(7)  STEP_A(8)  STEP_A(9)  STEP_A(10) STEP_A(11)
        STEP_B(12) STEP_B(13) STEP_B(14) STEP_B(15) STEP_B(16) STEP_B(17)
        STEP_B(18) STEP_B(19) STEP_B(20) STEP_B(21) STEP_B(22) STEP_B(23)
#undef STEP_A
#undef STEP_B

        const f2 zij = zij_a + zij_b;
        const f2 zfo = zfo_a + zfo_b;

        const float ig = sigf(zij.x);
        const float tj = tanhf_(zij.y);
        const float fg = sigf(zfo.x + 1.0f);   // forget bias
        const float og = sigf(zfo.y);
        cstate = fg * cstate + ig * tj;
        hn = og * tanhf_(cstate);
        hsum += hn;

        // prefetch next step's cap add-in, rotate pipeline
        ecb = EcB[cp1][jc];
        x0 = x1; x1 = x2; x2 = x3;
        wi3 = wi4; wi4 = win;
        cp0 = cp1; cp1 = cp2; cp2 = cp3; cp3 = cp4; cp4 = cpn;
    }

    // ---- epilogue: mean-pool + MLP head -----------------------------------
    if (act) hmean[half][jc] = hsum * (1.f / (float)Tt);
    __syncthreads();

    if (j < 25) {
        #pragma unroll
        for (int p = 0; p < 2; ++p) {
            const int q = j + p * 25;
            float s = b1[q];
            #pragma unroll
            for (int k = 0; k < 24; ++k)
                s += hmean[half][k] * W1[k * 50 + q];
            a1buf[half][q] = (s > 0.f) ? s : (__expf(s) - 1.f);  // ELU
        }
    }
    __syncthreads();

    if (j < 6) {
        float s = b2[j];
        for (int q = 0; q < 50; ++q) s += a1buf[half][q] * W2[q * 6 + j];
        out[b * 6 + j] = sigf(s);
    }
}

// ---------------------------------------------------------------------------
extern "C" void kernel_launch(void* const* d_in, const int* in_sizes, int n_in,
                              void* d_out, int out_size, void* d_ws, size_t ws_size,
                              hipStream_t stream)
{
    const int*   words = (const int*)d_in[0];
    const int*   caps  = (const int*)d_in[1];
    const float* Ew    = (const float*)d_in[2];
    const float* Ec    = (const float*)d_in[3];
    const float* Wl    = (const float*)d_in[4];
    const float* bl    = (const float*)d_in[5];
    const float* W1    = (const float*)d_in[6];
    const float* b1    = (const float*)d_in[7];
    const float* W2    = (const float*)d_in[8];
    const float* b2    = (const float*)d_in[9];
    float* out = (float*)d_out;
    float* EwW = (float*)d_ws;   // 50000 * 96 floats = 19.2 MB scratch

    ew_proj<<<(Vv + 63) / 64, 256, 0, stream>>>(Ew, Wl, EwW);
    lstm_head<<<Bb / 2, 64, 0, stream>>>(words, caps, Ec, Wl, bl, EwW,
                                         W1, b1, W2, b2, out);
}

// Round 11
// 377.821 us; speedup vs baseline: 1.0772x; 1.0762x over previous
//
#include <hip/hip_runtime.h>

typedef float f2 __attribute__((ext_vector_type(2)));

constexpr int Tt = 512;    // sequence length
constexpr int Bb = 256;    // batch
constexpr int Ee = 200;    // word-embedding dim
constexpr int Gg = 96;     // 4*H
constexpr int Vv = 50000;  // vocab

__device__ __forceinline__ float fast_rcp(float x) { return __builtin_amdgcn_rcpf(x); }
__device__ __forceinline__ float sigf(float x) { return fast_rcp(1.f + __expf(-x)); }
__device__ __forceinline__ float tanhf_(float x) {
    float e = __expf(2.f * x);
    return 1.f - 2.f * fast_rcp(e + 1.f);
}

// ---------------------------------------------------------------------------
// Kernel A: EwW[w][j*4+c] = sum_k Ew[w][k] * Wl[k][c*24+j]   (gate-interleaved)
// UNCHANGED from round 10 (single-change discipline; its counters become
// visible next round once lstm_head drops below it).
// ---------------------------------------------------------------------------
__global__ __launch_bounds__(256) void ew_proj(const float* __restrict__ Ew,
                                               const float* __restrict__ Wl,
                                               float* __restrict__ EwW)
{
    __shared__ float As[8][64];   // [k][m]
    __shared__ float Bs[8][96];   // [k][gate-interleaved col]
    const int tid = threadIdx.x;
    const int w0  = blockIdx.x * 64;
    const int tr  = tid >> 4;        // 0..15 -> rows tr*4..+3
    const int tc  = tid & 15;        // 0..15 -> cols tc*6..+5
    const int am  = tid >> 2;        // 0..63  (A stage row)
    const int ak  = (tid & 3) * 2;   // 0,2,4,6 (A stage k pair)
    const int bk  = tid >> 5;        // 0..7   (B stage k)
    const int bg  = (tid & 31) * 3;  // 0..93  (B stage col group)

    const int wA = w0 + am;
    const float* aptr = Ew + (long)((wA < Vv) ? wA : (Vv - 1)) * Ee + ak;
    const float* bptr = Wl + bk * Gg + bg;
    int gp[3];
    #pragma unroll
    for (int u = 0; u < 3; ++u) { const int g = bg + u; gp[u] = (g % 24) * 4 + g / 24; }

    // prologue: stage k0=0 tile into registers
    f2    avr  = *(const f2*)(aptr);
    float bvr0 = bptr[0], bvr1 = bptr[1], bvr2 = bptr[2];

    f2 acc[4][3] = {};

    for (int k0 = 0; k0 < Ee; k0 += 8) {
        // write staged registers to LDS
        As[ak][am]     = avr.x;
        As[ak + 1][am] = avr.y;
        Bs[bk][gp[0]] = bvr0; Bs[bk][gp[1]] = bvr1; Bs[bk][gp[2]] = bvr2;
        __syncthreads();

        // issue next tile's loads — latency hidden under compute below
        if (k0 + 8 < Ee) {
            avr  = *(const f2*)(aptr + k0 + 8);
            const long bo = (long)(k0 + 8) * Gg;
            bvr0 = bptr[bo + 0]; bvr1 = bptr[bo + 1]; bvr2 = bptr[bo + 2];
        }

        #pragma unroll
        for (int kk = 0; kk < 8; ++kk) {
            const float4 a4 = *(const float4*)&As[kk][tr * 4];
            f2 b[3];
            #pragma unroll
            for (int u = 0; u < 3; ++u) b[u] = *(const f2*)&Bs[kk][tc * 6 + u * 2];
            #pragma unroll
            for (int i = 0; i < 4; ++i) {
                const float ai = (&a4.x)[i];
                f2 a2 = {ai, ai};
                #pragma unroll
                for (int u = 0; u < 3; ++u) acc[i][u] += a2 * b[u];
            }
        }
        __syncthreads();
    }
    #pragma unroll
    for (int i = 0; i < 4; ++i) {
        const int w = w0 + tr * 4 + i;
        if (w < Vv) {
            #pragma unroll
            for (int u = 0; u < 3; ++u)
                *(f2*)(EwW + (long)w * Gg + tc * 6 + u * 2) = acc[i][u];
        }
    }
}

// ---------------------------------------------------------------------------
// Kernel C v3: sequential LSTM + mean-pool + MLP head.
// 1 chain per wave (grid = 256). Lane u (<24) owns ALL FOUR gates of unit u:
// no cross-lane gate combine. h-broadcast via v_readlane (VALU, ~2cy) instead
// of DS ops -> no DS latency on the serial path. U weights (96 floats/lane)
// kept live by an IN-LOOP asm keep-alive (round-10 showed an out-of-loop pin
// does not survive LLVM's rematerialization).
// ---------------------------------------------------------------------------
#define REP24(M) M(0)M(1)M(2)M(3)M(4)M(5)M(6)M(7)M(8)M(9)M(10)M(11) \
                 M(12)M(13)M(14)M(15)M(16)M(17)M(18)M(19)M(20)M(21)M(22)M(23)

__global__ __launch_bounds__(64, 1) void lstm_head(
    const int* __restrict__ words, const int* __restrict__ caps,
    const float* __restrict__ Ec,  const float* __restrict__ Wl,
    const float* __restrict__ bl,  const float* __restrict__ EwW,
    const float* __restrict__ W1,  const float* __restrict__ b1,
    const float* __restrict__ W2,  const float* __restrict__ b2,
    float* __restrict__ out)
{
    __shared__ float4 EcB[3][24];     // cap -> per-unit (i,j,f,o) incl. b_lstm
    __shared__ float  hmean[24];
    __shared__ float  a1buf[50];

    const int lane = threadIdx.x;
    const int u    = (lane < 24) ? lane : 23;   // clamp; lanes>=24 do dummy work
    const int b    = blockIdx.x;

    // EcB[cap][unit] = Ec[cap] @ Wl[200:203] + b_lstm   (gate-interleaved)
    for (int e = lane; e < 72; e += 64) {
        const int cap = e / 24, jj = e % 24;
        float4 v;
        #pragma unroll
        for (int c = 0; c < 4; ++c) {
            float s = bl[c * 24 + jj];
            #pragma unroll
            for (int kk = 0; kk < 3; ++kk)
                s += Ec[cap * 3 + kk] * Wl[(200 + kk) * Gg + c * 24 + jj];
            (&v.x)[c] = s;
        }
        EcB[cap][jj] = v;
    }
    __syncthreads();

    // U weights: lane u's 4 gate-columns of all 24 k-rows (96 scalars, coalesced)
#define DECL_UK(K) float ui##K, uj##K, uf##K, uo##K;
    REP24(DECL_UK)
#undef DECL_UK
#define LOAD_UK(K) { const float* p_ = Wl + (203 + K) * Gg + u;  \
                     ui##K = p_[0];  uj##K = p_[24];             \
                     uf##K = p_[48]; uo##K = p_[72]; }
    REP24(LOAD_UK)
#undef LOAD_UK

    const int* wrow = words + b * Tt;
    const int* crow = caps  + b * Tt;
    const int  off  = u * 4;

    // software pipeline: x ready for t..t+2, issued at t for t+3
    float4 x0 = *(const float4*)(EwW + (long)wrow[0] * Gg + off);
    float4 x1 = *(const float4*)(EwW + (long)wrow[1] * Gg + off);
    float4 x2 = *(const float4*)(EwW + (long)wrow[2] * Gg + off);
    int wi3 = wrow[3], wi4 = wrow[4];
    int cp0 = crow[0], cp1 = crow[1], cp2 = crow[2], cp3 = crow[3], cp4 = crow[4];

    float4 ecb = EcB[cp0][u];
    float cst = 0.f, hsum = 0.f, hn = 0.f;

    for (int t = 0; t < Tt; ++t) {
        // issue gather for t+3, index loads for t+5 (latency-tolerant)
        const float4 x3 = *(const float4*)(EwW + (long)wi3 * Gg + off);
        const int tn  = (t + 5 < Tt) ? (t + 5) : (Tt - 1);
        const int win = wrow[tn];
        const int cpn = crow[tn];

        // IN-LOOP keep-alive: forces all 96 U values into VGPRs every
        // iteration, making rematerialization pointless (round-10 lesson:
        // an out-of-loop pin does NOT keep them resident).
        asm volatile("" :: "v"(ui0),"v"(uj0),"v"(uf0),"v"(uo0),
                           "v"(ui1),"v"(uj1),"v"(uf1),"v"(uo1),
                           "v"(ui2),"v"(uj2),"v"(uf2),"v"(uo2));
        asm volatile("" :: "v"(ui3),"v"(uj3),"v"(uf3),"v"(uo3),
                           "v"(ui4),"v"(uj4),"v"(uf4),"v"(uo4),
                           "v"(ui5),"v"(uj5),"v"(uf5),"v"(uo5));
        asm volatile("" :: "v"(ui6),"v"(uj6),"v"(uf6),"v"(uo6),
                           "v"(ui7),"v"(uj7),"v"(uf7),"v"(uo7),
                           "v"(ui8),"v"(uj8),"v"(uf8),"v"(uo8));
        asm volatile("" :: "v"(ui9),"v"(uj9),"v"(uf9),"v"(uo9),
                           "v"(ui10),"v"(uj10),"v"(uf10),"v"(uo10),
                           "v"(ui11),"v"(uj11),"v"(uf11),"v"(uo11));
        asm volatile("" :: "v"(ui12),"v"(uj12),"v"(uf12),"v"(uo12),
                           "v"(ui13),"v"(uj13),"v"(uf13),"v"(uo13),
                           "v"(ui14),"v"(uj14),"v"(uf14),"v"(uo14));
        asm volatile("" :: "v"(ui15),"v"(uj15),"v"(uf15),"v"(uo15),
                           "v"(ui16),"v"(uj16),"v"(uf16),"v"(uo16),
                           "v"(ui17),"v"(uj17),"v"(uf17),"v"(uo17));
        asm volatile("" :: "v"(ui18),"v"(uj18),"v"(uf18),"v"(uo18),
                           "v"(ui19),"v"(uj19),"v"(uf19),"v"(uo19),
                           "v"(ui20),"v"(uj20),"v"(uf20),"v"(uo20));
        asm volatile("" :: "v"(ui21),"v"(uj21),"v"(uf21),"v"(uo21),
                           "v"(ui22),"v"(uj22),"v"(uf22),"v"(uo22),
                           "v"(ui23),"v"(uj23),"v"(uf23),"v"(uo23));

        float zi = x0.x + ecb.x;
        float zj = x0.y + ecb.y;
        float zf = x0.z + ecb.z;
        float zo = x0.w + ecb.w;

        const int hni = __float_as_int(hn);  // h[k] lives in lane k
#define KSTEP(K) { const float hk_ = __int_as_float(                     \
                       __builtin_amdgcn_readlane(hni, K));               \
                   zi += hk_ * ui##K;  zj += hk_ * uj##K;                \
                   zf += hk_ * uf##K;  zo += hk_ * uo##K; }
        REP24(KSTEP)
#undef KSTEP

        const float ig = sigf(zi);
        const float tj = tanhf_(zj);
        const float fg = sigf(zf + 1.0f);   // forget bias
        const float og = sigf(zo);
        cst = fg * cst + ig * tj;
        hn  = og * tanhf_(cst);
        hsum += hn;

        // prefetch next step's cap add-in, rotate pipeline
        ecb = EcB[cp1][u];
        x0 = x1; x1 = x2; x2 = x3;
        wi3 = wi4; wi4 = win;
        cp0 = cp1; cp1 = cp2; cp2 = cp3; cp3 = cp4; cp4 = cpn;
    }

    // ---- epilogue: mean-pool + MLP head -----------------------------------
    if (lane < 24) hmean[lane] = hsum * (1.f / (float)Tt);
    __syncthreads();

    if (lane < 50) {
        float s = b1[lane];
        #pragma unroll
        for (int k = 0; k < 24; ++k)
            s += hmean[k] * W1[k * 50 + lane];
        a1buf[lane] = (s > 0.f) ? s : (__expf(s) - 1.f);  // ELU
    }
    __syncthreads();

    if (lane < 6) {
        float s = b2[lane];
        for (int q = 0; q < 50; ++q) s += a1buf[q] * W2[q * 6 + lane];
        out[b * 6 + lane] = sigf(s);
    }
}

// ---------------------------------------------------------------------------
extern "C" void kernel_launch(void* const* d_in, const int* in_sizes, int n_in,
                              void* d_out, int out_size, void* d_ws, size_t ws_size,
                              hipStream_t stream)
{
    const int*   words = (const int*)d_in[0];
    const int*   caps  = (const int*)d_in[1];
    const float* Ew    = (const float*)d_in[2];
    const float* Ec    = (const float*)d_in[3];
    const float* Wl    = (const float*)d_in[4];
    const float* bl    = (const float*)d_in[5];
    const float* W1    = (const float*)d_in[6];
    const float* b1    = (const float*)d_in[7];
    const float* W2    = (const float*)d_in[8];
    const float* b2    = (const float*)d_in[9];
    float* out = (float*)d_out;
    float* EwW = (float*)d_ws;   // 50000 * 96 floats = 19.2 MB scratch

    ew_proj<<<(Vv + 63) / 64, 256, 0, stream>>>(Ew, Wl, EwW);
    lstm_head<<<Bb, 64, 0, stream>>>(words, caps, Ec, Wl, bl, EwW,
                                     W1, b1, W2, b2, out);
}